// Round 7
// baseline (270.139 us; speedup 1.0000x reference)
//
#include <hip/hip_runtime.h>
#include <math.h>

#define HID 32
#define TDIM 128
#define NNODE 100000
#define NEDGE 800000
#define NGRAPH 512
#define SCAN_BLK 1024
#define NBLK1 ((NNODE + SCAN_BLK - 1) / SCAN_BLK)   // 98
#define TPW 4   // edge tiles (of 16) per wave
#define NFRAG 18

typedef __attribute__((ext_vector_type(8))) short bf16x8;
typedef __attribute__((ext_vector_type(4))) float f32x4;

#define MFMA16(a, b, c) __builtin_amdgcn_mfma_f32_16x16x32_bf16(a, b, c, 0, 0, 0)

__device__ __forceinline__ float silu_f(float v) {
    return v * __builtin_amdgcn_rcpf(1.0f + __expf(-v));
}
__device__ __forceinline__ float sigmoid_f(float v) {
    return __builtin_amdgcn_rcpf(1.0f + __expf(-v));
}
__device__ __forceinline__ unsigned int bf16r(float f) {
    unsigned int u = __float_as_uint(f);
    return (u + 0x7FFFu + ((u >> 16) & 1u)) >> 16;   // RNE (cold paths)
}
__device__ __forceinline__ float bf16tof(unsigned int h) {
    return __uint_as_float(h << 16);
}
// pack two f32 -> two bf16 (round-half-up) in 3 VALU ops via v_perm_b32
__device__ __forceinline__ unsigned int pk2(float a, float b) {
    unsigned int ia = __float_as_uint(a) + 0x8000u;
    unsigned int ib = __float_as_uint(b) + 0x8000u;
    return __builtin_amdgcn_perm(ib, ia, 0x07060302u);
}
__device__ __forceinline__ bf16x8 pack8(f32x4 a, f32x4 b) {
    union { unsigned int u[4]; bf16x8 v; } r;
    r.u[0] = pk2(a[0], a[1]);
    r.u[1] = pk2(a[2], a[3]);
    r.u[2] = pk2(b[0], b[1]);
    r.u[3] = pk2(b[2], b[3]);
    return r.v;
}

// ---------------- K1: time MLP ----------------
__global__ void time_mlp_kernel(const float* __restrict__ timein,
                                const float* __restrict__ w1, const float* __restrict__ b1,
                                const float* __restrict__ w2, const float* __restrict__ b2,
                                float* __restrict__ ss) {
    __shared__ float t[TDIM];
    __shared__ float h[2 * HID];
    const int g = blockIdx.x;
    const int c = threadIdx.x;  // 0..63
    t[c]      = timein[g * TDIM + c];
    t[64 + c] = timein[g * TDIM + 64 + c];
    __syncthreads();
    float acc = b1[c];
#pragma unroll
    for (int k = 0; k < TDIM; ++k) acc = fmaf(t[k], w1[k * 2 * HID + c], acc);
    h[c] = silu_f(acc);
    __syncthreads();
    float acc2 = b2[c];
#pragma unroll
    for (int k = 0; k < 2 * HID; ++k) acc2 = fmaf(h[k], w2[k * 2 * HID + c], acc2);
    ss[g * 2 * HID + c] = acc2;
}

// ---------------- K2: fused node-pre + histogram + weight-fragment prep ----------------
__global__ void fused_pre_kernel(const float* __restrict__ x, const int* __restrict__ batch,
                                 const float* __restrict__ ss, const int* __restrict__ ei,
                                 unsigned short* __restrict__ x_bf, int* __restrict__ cnt_int,
                                 const float* __restrict__ msg_w1, const float* __restrict__ msg_w2,
                                 const float* __restrict__ gate_w, const float* __restrict__ w_dist,
                                 const float* __restrict__ coord_w1, const float* __restrict__ comb_w1,
                                 const float* __restrict__ comb_w2,
                                 unsigned short* __restrict__ wf) {
    const int t = blockIdx.x * blockDim.x + threadIdx.x;  // N*32 threads
    {
        const int n = t >> 5, c = t & 31;
        const int g = batch[n];
        const float scale = ss[g * 64 + c];
        const float shift = ss[g * 64 + 32 + c];
        const float v = x[t];
        x_bf[t] = (unsigned short)bf16r(silu_f(fmaf(v, scale, v) + shift));
    }
    if (t < NEDGE) atomicAdd(&cnt_int[ei[NEDGE + t]], 1);
    if (t < NFRAG * 512) {
        const int frag = t >> 9;
        const int idx = t & 511;
        const int lane = idx >> 3, j = idx & 7;
        const int n16 = lane & 15, k = (lane >> 4) * 8 + j;
        const float* W; int kt = 0, nt;
        if (frag < 4)       { W = msg_w1;   kt = frag >> 1;        nt = frag & 1; }
        else if (frag < 6)  { W = msg_w2;   nt = frag - 4; }
        else if (frag < 8)  { W = gate_w;   nt = frag - 6; }
        else if (frag < 10) { W = w_dist;   nt = frag - 8; }
        else if (frag < 12) { W = coord_w1; nt = frag - 10; }
        else if (frag < 16) { W = comb_w1;  kt = (frag - 12) >> 1; nt = (frag - 12) & 1; }
        else                { W = comb_w2;  nt = frag - 16; }
        wf[t] = (unsigned short)bf16r(W[(kt * 32 + k) * 32 + nt * 16 + n16]);
    }
}

// ---------------- K4: exclusive scan ----------------
__global__ void scan1_kernel(const int* __restrict__ cnt_int, int* __restrict__ part,
                             int* __restrict__ blk) {
    __shared__ int s[SCAN_BLK];
    const int tid = threadIdx.x;
    const int i = blockIdx.x * SCAN_BLK + tid;
    const int v = (i < NNODE) ? cnt_int[i] : 0;
    s[tid] = v;
    __syncthreads();
    for (int off = 1; off < SCAN_BLK; off <<= 1) {
        int t = (tid >= off) ? s[tid - off] : 0;
        __syncthreads();
        s[tid] += t;
        __syncthreads();
    }
    part[i] = s[tid] - v;
    if (tid == SCAN_BLK - 1) blk[blockIdx.x] = s[tid];
}

__global__ void scan2_kernel(int* __restrict__ blk, int* __restrict__ blk_off) {
    __shared__ int s[128];
    const int tid = threadIdx.x;
    const int v = (tid < NBLK1) ? blk[tid] : 0;
    s[tid] = v;
    __syncthreads();
    for (int off = 1; off < 128; off <<= 1) {
        int t = (tid >= off) ? s[tid - off] : 0;
        __syncthreads();
        s[tid] += t;
        __syncthreads();
    }
    blk_off[tid] = s[tid] - v;
}

__global__ void scan3_kernel(const int* __restrict__ part, const int* __restrict__ blk_off,
                             int* __restrict__ offsets, int* __restrict__ cursor) {
    const int i = blockIdx.x * blockDim.x + threadIdx.x;
    if (i >= NNODE) return;
    const int o = part[i] + blk_off[i >> 10];
    offsets[i] = o;
    cursor[i] = o;
}

// ---------------- K5: MFMA edge kernel (R5 structure + next-tile prefetch) ----------------
__global__ __launch_bounds__(256) void edge_mfma_kernel(
    const int* __restrict__ ei, const unsigned short* __restrict__ x_bf,
    const float* __restrict__ pos,
    const float* __restrict__ rbf_means, const float* __restrict__ rbf_betas,
    const unsigned short* __restrict__ wf,
    const float* __restrict__ msg_b1, const float* __restrict__ msg_b2,
    const float* __restrict__ gate_b, const float* __restrict__ coord_b1,
    const float* __restrict__ coord_w2, const float* __restrict__ coord_b2,
    int* __restrict__ cursor, unsigned short* __restrict__ m_buf,
    float* __restrict__ pu_buf) {
    __shared__ float lmat[4][16 * 36];
    __shared__ float lcut[4][16];
    __shared__ float lpd[4][16][4];
    __shared__ int   lslot[4][16];

    const int tid = threadIdx.x;
    const int wv = tid >> 6, lane = tid & 63;
    const int m16 = lane & 15, q = lane >> 4;
    float* Lm = lmat[wv];

    bf16x8 WF[12];
#pragma unroll
    for (int f = 0; f < 12; ++f) WF[f] = *(const bf16x8*)(wf + f * 512 + lane * 8);

    const float b1c0 = msg_b1[m16],   b1c1 = msg_b1[16 + m16];
    const float b2c0 = msg_b2[m16],   b2c1 = msg_b2[16 + m16];
    const float gbc0 = gate_b[m16],   gbc1 = gate_b[16 + m16];
    const float cb10 = coord_b1[m16], cb11 = coord_b1[16 + m16];
    const float cw20 = coord_w2[m16], cw21 = coord_w2[16 + m16];
    const float cb2  = coord_b2[0];
    const float4 rm0 = *(const float4*)(rbf_means + q * 8);
    const float4 rm1 = *(const float4*)(rbf_means + q * 8 + 4);
    const float4 rb0 = *(const float4*)(rbf_betas + q * 8);
    const float4 rb1 = *(const float4*)(rbf_betas + q * 8 + 4);

    const int wave_id = blockIdx.x * 4 + wv;
    const int ebase = wave_id * TPW * 16;
    const f32x4 z = {0.f, 0.f, 0.f, 0.f};

    // prologue: load tile 0
    int vi, vj;
    bf16x8 xi, xj;
    float pi0, pi1, pi2, pj0, pj1, pj2;
    {
        const int e = ebase + m16;
        vi = ei[e]; vj = ei[NEDGE + e];
        xi = *(const bf16x8*)(x_bf + (size_t)vi * HID + q * 8);
        xj = *(const bf16x8*)(x_bf + (size_t)vj * HID + q * 8);
        pi0 = pos[vi * 3 + 0]; pi1 = pos[vi * 3 + 1]; pi2 = pos[vi * 3 + 2];
        pj0 = pos[vj * 3 + 0]; pj1 = pos[vj * 3 + 1]; pj2 = pos[vj * 3 + 2];
    }

#pragma unroll 1
    for (int t = 0; t < TPW; ++t) {
        // prefetch tile t+1 while computing tile t
        int nvi = 0, nvj = 0;
        bf16x8 nxi = {}, nxj = {};
        float npi0 = 0.f, npi1 = 0.f, npi2 = 0.f, npj0 = 0.f, npj1 = 0.f, npj2 = 0.f;
        const bool more = (t + 1 < TPW);
        if (more) {
            const int e = ebase + (t + 1) * 16 + m16;
            nvi = ei[e]; nvj = ei[NEDGE + e];
            nxi = *(const bf16x8*)(x_bf + (size_t)nvi * HID + q * 8);
            nxj = *(const bf16x8*)(x_bf + (size_t)nvj * HID + q * 8);
            npi0 = pos[nvi * 3 + 0]; npi1 = pos[nvi * 3 + 1]; npi2 = pos[nvi * 3 + 2];
            npj0 = pos[nvj * 3 + 0]; npj1 = pos[nvj * 3 + 1]; npj2 = pos[nvj * 3 + 2];
        }

        const float p0 = pi0 - pj0;
        const float p1 = pi1 - pj1;
        const float p2 = pi2 - pj2;
        const float dist = sqrtf(p0 * p0 + p1 * p1 + p2 * p2);
        const float dcl = fminf(dist, 5.0f);
        const float cutoff = 0.5f * (__cosf(dcl * 0.6283185307179586f) + 1.0f);
        const float edm = __expf(-dist);
        if (q == 0) {
            lslot[wv][m16] = atomicAdd(&cursor[vj], 1);
            lcut[wv][m16] = cutoff;
            lpd[wv][m16][0] = p0; lpd[wv][m16][1] = p1; lpd[wv][m16][2] = p2;
        }

        // L1: h = silu(cat(xi,xj) @ msg_w1 + b1)
        f32x4 h0 = MFMA16(xi, WF[0], z); h0 = MFMA16(xj, WF[2], h0);
        f32x4 h1 = MFMA16(xi, WF[1], z); h1 = MFMA16(xj, WF[3], h1);
#pragma unroll
        for (int r = 0; r < 4; ++r) {
            Lm[(q * 4 + r) * 36 + m16]      = silu_f(h0[r] + b1c0);
            Lm[(q * 4 + r) * 36 + 16 + m16] = silu_f(h1[r] + b1c1);
        }
        __builtin_amdgcn_s_waitcnt(0xC07F);  // lgkmcnt(0)
        f32x4 ha0 = *(const f32x4*)(Lm + m16 * 36 + q * 8);
        f32x4 ha1 = *(const f32x4*)(Lm + m16 * 36 + q * 8 + 4);
        const bf16x8 hf = pack8(ha0, ha1);

        // L2, gate, dist_emb
        f32x4 am0 = MFMA16(hf, WF[4], z), am1 = MFMA16(hf, WF[5], z);
        f32x4 g0  = MFMA16(xj, WF[6], z), g1  = MFMA16(xj, WF[7], z);
        float rv[8];
        { float d;
          d = edm - rm0.x; rv[0] = __expf(-rb0.x * d * d);
          d = edm - rm0.y; rv[1] = __expf(-rb0.y * d * d);
          d = edm - rm0.z; rv[2] = __expf(-rb0.z * d * d);
          d = edm - rm0.w; rv[3] = __expf(-rb0.w * d * d);
          d = edm - rm1.x; rv[4] = __expf(-rb1.x * d * d);
          d = edm - rm1.y; rv[5] = __expf(-rb1.y * d * d);
          d = edm - rm1.z; rv[6] = __expf(-rb1.z * d * d);
          d = edm - rm1.w; rv[7] = __expf(-rb1.w * d * d); }
        bf16x8 rf;
        { union { unsigned int u[4]; bf16x8 v; } rr;
          rr.u[0] = pk2(rv[0], rv[1]); rr.u[1] = pk2(rv[2], rv[3]);
          rr.u[2] = pk2(rv[4], rv[5]); rr.u[3] = pk2(rv[6], rv[7]);
          rf = rr.v; }
        f32x4 d0 = MFMA16(rf, WF[8], z), d1 = MFMA16(rf, WF[9], z);

        __builtin_amdgcn_s_waitcnt(0xC07F);
#pragma unroll
        for (int r = 0; r < 4; ++r) {
            const float cu = lcut[wv][q * 4 + r];
            const float mv0 = silu_f(am0[r] + b2c0) * sigmoid_f(g0[r] + gbc0) * cu * d0[r];
            const float mv1 = silu_f(am1[r] + b2c1) * sigmoid_f(g1[r] + gbc1) * cu * d1[r];
            Lm[(q * 4 + r) * 36 + m16]      = mv0;
            Lm[(q * 4 + r) * 36 + 16 + m16] = mv1;
        }
        __builtin_amdgcn_s_waitcnt(0xC07F);
        f32x4 ma0 = *(const f32x4*)(Lm + m16 * 36 + q * 8);
        f32x4 ma1 = *(const f32x4*)(Lm + m16 * 36 + q * 8 + 4);
        const bf16x8 mf = pack8(ma0, ma1);

        // coord layer + per-edge scalar s
        f32x4 c0 = MFMA16(mf, WF[10], z), c1 = MFMA16(mf, WF[11], z);
        float pp[4];
#pragma unroll
        for (int r = 0; r < 4; ++r)
            pp[r] = silu_f(c0[r] + cb10) * cw20 + silu_f(c1[r] + cb11) * cw21;
#pragma unroll
        for (int off = 1; off < 16; off <<= 1) {
#pragma unroll
            for (int r = 0; r < 4; ++r) pp[r] += __shfl_xor(pp[r], off);
        }

        {
            const int em = lane >> 2, ch = lane & 3;
            f32x4 s0 = *(const f32x4*)(Lm + em * 36 + ch * 8);
            f32x4 s1 = *(const f32x4*)(Lm + em * 36 + ch * 8 + 4);
            const bf16x8 mb = pack8(s0, s1);
            const int sl = lslot[wv][em];
            *(bf16x8*)(m_buf + (size_t)sl * HID + ch * 8) = mb;
        }
        if (m16 < 4) {
            const int ep = q * 4 + m16;
            const float sv = (m16 == 0 ? pp[0] : (m16 == 1 ? pp[1] : (m16 == 2 ? pp[2] : pp[3]))) + cb2;
            const int sl = lslot[wv][ep];
            ((float4*)pu_buf)[sl] = make_float4(lpd[wv][ep][0] * sv, lpd[wv][ep][1] * sv,
                                                lpd[wv][ep][2] * sv, 0.0f);
        }

        if (more) {
            vi = nvi; vj = nvj; xi = nxi; xj = nxj;
            pi0 = npi0; pi1 = npi1; pi2 = npi2;
            pj0 = npj0; pj1 = npj1; pj2 = npj2;
        }
    }
}

// ---------------- K6: fused gather + node post (MFMA, wave = 16 nodes) ----------------
__global__ __launch_bounds__(256) void node_post_mfma_kernel(
    const unsigned short* __restrict__ x_bf, const unsigned short* __restrict__ m_buf,
    const float* __restrict__ pu_buf,
    const int* __restrict__ offsets, const int* __restrict__ cnt_int,
    const float* __restrict__ pos, const unsigned short* __restrict__ wf,
    const float* __restrict__ comb_b1, const float* __restrict__ comb_b2,
    float* __restrict__ out_x, float* __restrict__ out_pos) {
    __shared__ float Lh[4][16 * 36];
    __shared__ float Lx[4][16 * 36];
    const int tid = threadIdx.x;
    const int wv = tid >> 6, lane = tid & 63;
    const int m16 = lane & 15, q = lane >> 4;
    const int wave_id = blockIdx.x * 4 + wv;
    if (wave_id * 16 >= NNODE) return;
    const int n = wave_id * 16 + m16;
    float* LH = Lh[wv];
    float* LX = Lx[wv];

    bf16x8 F[6];
#pragma unroll
    for (int f = 0; f < 6; ++f) F[f] = *(const bf16x8*)(wf + (12 + f) * 512 + lane * 8);
    const float b1c0 = comb_b1[m16], b1c1 = comb_b1[16 + m16];
    const float b2c0 = comb_b2[m16], b2c1 = comb_b2[16 + m16];

    const bf16x8 xa = *(const bf16x8*)(x_bf + (size_t)n * HID + q * 8);
    {
        f32x4 xd0, xd1;
#pragma unroll
        for (int jj = 0; jj < 4; ++jj) {
            xd0[jj] = bf16tof((unsigned short)xa[jj]);
            xd1[jj] = bf16tof((unsigned short)xa[4 + jj]);
        }
        *(f32x4*)(LX + m16 * 36 + q * 8) = xd0;
        *(f32x4*)(LX + m16 * 36 + q * 8 + 4) = xd1;
    }

    // gather m_i: 2-way unrolled (two loads in flight)
    const int off = offsets[n];
    const int deg = cnt_int[n];
    float acc0[8] = {0.f, 0.f, 0.f, 0.f, 0.f, 0.f, 0.f, 0.f};
    float acc1[8] = {0.f, 0.f, 0.f, 0.f, 0.f, 0.f, 0.f, 0.f};
    int d = 0;
    for (; d + 2 <= deg; d += 2) {
        const bf16x8 m0 = *(const bf16x8*)(m_buf + (size_t)(off + d) * HID + q * 8);
        const bf16x8 m1 = *(const bf16x8*)(m_buf + (size_t)(off + d + 1) * HID + q * 8);
#pragma unroll
        for (int jj = 0; jj < 8; ++jj) {
            acc0[jj] += bf16tof((unsigned short)m0[jj]);
            acc1[jj] += bf16tof((unsigned short)m1[jj]);
        }
    }
    if (d < deg) {
        const bf16x8 m0 = *(const bf16x8*)(m_buf + (size_t)(off + d) * HID + q * 8);
#pragma unroll
        for (int jj = 0; jj < 8; ++jj) acc0[jj] += bf16tof((unsigned short)m0[jj]);
    }
    bf16x8 mi;
    { union { unsigned int u[4]; bf16x8 v; } rr;
      rr.u[0] = pk2(acc0[0] + acc1[0], acc0[1] + acc1[1]);
      rr.u[1] = pk2(acc0[2] + acc1[2], acc0[3] + acc1[3]);
      rr.u[2] = pk2(acc0[4] + acc1[4], acc0[5] + acc1[5]);
      rr.u[3] = pk2(acc0[6] + acc1[6], acc0[7] + acc1[7]);
      mi = rr.v; }

    float a0 = 0.f, a1 = 0.f, a2 = 0.f;
    for (int dd = q; dd < deg; dd += 4) {
        const float4 p = ((const float4*)pu_buf)[off + dd];
        a0 += p.x; a1 += p.y; a2 += p.z;
    }
    a0 += __shfl_xor(a0, 16); a0 += __shfl_xor(a0, 32);
    a1 += __shfl_xor(a1, 16); a1 += __shfl_xor(a1, 32);
    a2 += __shfl_xor(a2, 16); a2 += __shfl_xor(a2, 32);

    const f32x4 z = {0.f, 0.f, 0.f, 0.f};
    f32x4 h0 = MFMA16(xa, F[0], z); h0 = MFMA16(mi, F[2], h0);
    f32x4 h1 = MFMA16(xa, F[1], z); h1 = MFMA16(mi, F[3], h1);
#pragma unroll
    for (int r = 0; r < 4; ++r) {
        LH[(q * 4 + r) * 36 + m16]      = silu_f(h0[r] + b1c0);
        LH[(q * 4 + r) * 36 + 16 + m16] = silu_f(h1[r] + b1c1);
    }
    __builtin_amdgcn_s_waitcnt(0xC07F);
    f32x4 ha0 = *(const f32x4*)(LH + m16 * 36 + q * 8);
    f32x4 ha1 = *(const f32x4*)(LH + m16 * 36 + q * 8 + 4);
    const bf16x8 hf = pack8(ha0, ha1);

    f32x4 c0 = MFMA16(hf, F[4], z), c1 = MFMA16(hf, F[5], z);
#pragma unroll
    for (int r = 0; r < 4; ++r) {
        const float xv0 = LX[(q * 4 + r) * 36 + m16];
        const float xv1 = LX[(q * 4 + r) * 36 + 16 + m16];
        LH[(q * 4 + r) * 36 + m16]      = silu_f(xv0 + c0[r] + b2c0);
        LH[(q * 4 + r) * 36 + 16 + m16] = silu_f(xv1 + c1[r] + b2c1);
    }
    __builtin_amdgcn_s_waitcnt(0xC07F);
    {
        const int row = lane >> 2, col = (lane & 3) * 8;
        f32x4 o0 = *(const f32x4*)(LH + row * 36 + col);
        f32x4 o1 = *(const f32x4*)(LH + row * 36 + col + 4);
        float* dst = out_x + (size_t)(wave_id * 16 + row) * HID + col;
        *(f32x4*)dst = o0;
        *(f32x4*)(dst + 4) = o1;
    }
    if (q == 0) {
        const float inv = __builtin_amdgcn_rcpf(fmaxf((float)deg, 1.0f));
        out_pos[n * 3 + 0] = fmaf(a0, inv, pos[n * 3 + 0]);
        out_pos[n * 3 + 1] = fmaf(a1, inv, pos[n * 3 + 1]);
        out_pos[n * 3 + 2] = fmaf(a2, inv, pos[n * 3 + 2]);
    }
}

// ---------------- launch ----------------
extern "C" void kernel_launch(void* const* d_in, const int* in_sizes, int n_in,
                              void* d_out, int out_size, void* d_ws, size_t ws_size,
                              hipStream_t stream) {
    const float* x        = (const float*)d_in[0];
    const int*   ei       = (const int*)d_in[1];
    const float* pos      = (const float*)d_in[2];
    const float* timein   = (const float*)d_in[3];
    const int*   batch    = (const int*)d_in[4];
    const float* rbfm     = (const float*)d_in[5];
    const float* rbfb     = (const float*)d_in[6];
    const float* w_dist   = (const float*)d_in[7];
    const float* msg_w1   = (const float*)d_in[8];
    const float* msg_b1   = (const float*)d_in[9];
    const float* msg_w2   = (const float*)d_in[10];
    const float* msg_b2   = (const float*)d_in[11];
    const float* gate_w   = (const float*)d_in[12];
    const float* gate_b   = (const float*)d_in[13];
    const float* time_w1  = (const float*)d_in[14];
    const float* time_b1  = (const float*)d_in[15];
    const float* time_w2  = (const float*)d_in[16];
    const float* time_b2  = (const float*)d_in[17];
    const float* comb_w1  = (const float*)d_in[18];
    const float* comb_b1  = (const float*)d_in[19];
    const float* comb_w2  = (const float*)d_in[20];
    const float* comb_b2  = (const float*)d_in[21];
    const float* coord_w1 = (const float*)d_in[22];
    const float* coord_b1 = (const float*)d_in[23];
    const float* coord_w2 = (const float*)d_in[24];
    const float* coord_b2 = (const float*)d_in[25];

    char* w = (char*)d_ws;
    float* ss      = (float*)w;  w += (size_t)NGRAPH * 64 * 4;
    int*   cnt_int = (int*)w;    w += (size_t)NNODE * 4;
    int*   offsets = (int*)w;    w += (size_t)NNODE * 4;
    int*   cursor  = (int*)w;    w += (size_t)NNODE * 4;
    int*   part    = (int*)w;    w += (size_t)NBLK1 * SCAN_BLK * 4;
    int*   blk     = (int*)w;    w += 128 * 4;
    int*   blk_off = (int*)w;    w += 128 * 4;
    w = (char*)(((size_t)w + 15) & ~(size_t)15);
    unsigned short* x_bf = (unsigned short*)w;  w += (size_t)NNODE * HID * 2;
    unsigned short* wf   = (unsigned short*)w;  w += (size_t)NFRAG * 512 * 2;
    w = (char*)(((size_t)w + 15) & ~(size_t)15);
    unsigned short* m_buf = (unsigned short*)w; w += (size_t)NEDGE * HID * 2;
    float* pu_buf  = (float*)w;

    float* out_x   = (float*)d_out;
    float* out_pos = out_x + NNODE * HID;

    hipMemsetAsync(cnt_int, 0, (size_t)NNODE * 4, stream);
    time_mlp_kernel<<<NGRAPH, 64, 0, stream>>>(timein, time_w1, time_b1, time_w2, time_b2, ss);
    fused_pre_kernel<<<(NNODE * HID) / 256, 256, 0, stream>>>(x, batch, ss, ei, x_bf, cnt_int,
                                                              msg_w1, msg_w2, gate_w, w_dist,
                                                              coord_w1, comb_w1, comb_w2, wf);
    scan1_kernel<<<NBLK1, SCAN_BLK, 0, stream>>>(cnt_int, part, blk);
    scan2_kernel<<<1, 128, 0, stream>>>(blk, blk_off);
    scan3_kernel<<<(NNODE + 255) / 256, 256, 0, stream>>>(part, blk_off, offsets, cursor);
    edge_mfma_kernel<<<NEDGE / 256, 256, 0, stream>>>(ei, x_bf, pos, rbfm, rbfb, wf,
                                                      msg_b1, msg_b2, gate_b, coord_b1,
                                                      coord_w2, coord_b2,
                                                      cursor, m_buf, pu_buf);
    node_post_mfma_kernel<<<(NNODE / 16 + 3) / 4, 256, 0, stream>>>(x_bf, m_buf, pu_buf,
                                                                    offsets, cnt_int, pos, wf,
                                                                    comb_b1, comb_b2,
                                                                    out_x, out_pos);
}

// Round 8
// 242.110 us; speedup vs baseline: 1.1158x; 1.1158x over previous
//
#include <hip/hip_runtime.h>
#include <math.h>

#define HID 32
#define TDIM 128
#define NNODE 100000
#define NEDGE 800000
#define NGRAPH 512
#define SCAN_BLK 1024
#define NBLK1 ((NNODE + SCAN_BLK - 1) / SCAN_BLK)   // 98
#define TPW 4   // edge tiles (of 16) per wave
#define NFRAG 18

typedef __attribute__((ext_vector_type(8))) short bf16x8;
typedef __attribute__((ext_vector_type(4))) float f32x4;

#define MFMA16(a, b, c) __builtin_amdgcn_mfma_f32_16x16x32_bf16(a, b, c, 0, 0, 0)

__device__ __forceinline__ float silu_f(float v) {
    return v * __builtin_amdgcn_rcpf(1.0f + __expf(-v));
}
__device__ __forceinline__ float sigmoid_f(float v) {
    return __builtin_amdgcn_rcpf(1.0f + __expf(-v));
}
__device__ __forceinline__ unsigned int bf16r(float f) {
    unsigned int u = __float_as_uint(f);
    return (u + 0x7FFFu + ((u >> 16) & 1u)) >> 16;   // RNE (cold paths)
}
__device__ __forceinline__ float bf16tof(unsigned int h) {
    return __uint_as_float(h << 16);
}
// pack two f32 -> two bf16 (round-half-up) in 3 VALU ops via v_perm_b32
__device__ __forceinline__ unsigned int pk2(float a, float b) {
    unsigned int ia = __float_as_uint(a) + 0x8000u;
    unsigned int ib = __float_as_uint(b) + 0x8000u;
    return __builtin_amdgcn_perm(ib, ia, 0x07060302u);
}
__device__ __forceinline__ bf16x8 pack8(f32x4 a, f32x4 b) {
    union { unsigned int u[4]; bf16x8 v; } r;
    r.u[0] = pk2(a[0], a[1]);
    r.u[1] = pk2(a[2], a[3]);
    r.u[2] = pk2(b[0], b[1]);
    r.u[3] = pk2(b[2], b[3]);
    return r.v;
}

// ---------------- K1: time MLP + zero degree counters ----------------
__global__ void time_mlp_kernel(const float* __restrict__ timein,
                                const float* __restrict__ w1, const float* __restrict__ b1,
                                const float* __restrict__ w2, const float* __restrict__ b2,
                                float* __restrict__ ss, int* __restrict__ cnt_int) {
    // grid-stride zero of cnt_int (replaces hipMemsetAsync dispatch)
    for (int i = blockIdx.x * 64 + threadIdx.x; i < NNODE; i += NGRAPH * 64) cnt_int[i] = 0;

    __shared__ float t[TDIM];
    __shared__ float h[2 * HID];
    const int g = blockIdx.x;
    const int c = threadIdx.x;  // 0..63
    t[c]      = timein[g * TDIM + c];
    t[64 + c] = timein[g * TDIM + 64 + c];
    __syncthreads();
    float acc = b1[c];
#pragma unroll
    for (int k = 0; k < TDIM; ++k) acc = fmaf(t[k], w1[k * 2 * HID + c], acc);
    h[c] = silu_f(acc);
    __syncthreads();
    float acc2 = b2[c];
#pragma unroll
    for (int k = 0; k < 2 * HID; ++k) acc2 = fmaf(h[k], w2[k * 2 * HID + c], acc2);
    ss[g * 2 * HID + c] = acc2;
}

// ---------------- K2: fused node-pre + histogram + weight-fragment prep ----------------
__global__ void fused_pre_kernel(const float* __restrict__ x, const int* __restrict__ batch,
                                 const float* __restrict__ ss, const int* __restrict__ ei,
                                 unsigned short* __restrict__ x_bf, int* __restrict__ cnt_int,
                                 const float* __restrict__ msg_w1, const float* __restrict__ msg_w2,
                                 const float* __restrict__ gate_w, const float* __restrict__ w_dist,
                                 const float* __restrict__ coord_w1, const float* __restrict__ comb_w1,
                                 const float* __restrict__ comb_w2,
                                 unsigned short* __restrict__ wf) {
    const int t = blockIdx.x * blockDim.x + threadIdx.x;  // N*32 threads
    {
        const int n = t >> 5, c = t & 31;
        const int g = batch[n];
        const float scale = ss[g * 64 + c];
        const float shift = ss[g * 64 + 32 + c];
        const float v = x[t];
        x_bf[t] = (unsigned short)bf16r(silu_f(fmaf(v, scale, v) + shift));
    }
    if (t < NEDGE) atomicAdd(&cnt_int[ei[NEDGE + t]], 1);
    if (t < NFRAG * 512) {
        const int frag = t >> 9;
        const int idx = t & 511;
        const int lane = idx >> 3, j = idx & 7;
        const int n16 = lane & 15, k = (lane >> 4) * 8 + j;
        const float* W; int kt = 0, nt;
        if (frag < 4)       { W = msg_w1;   kt = frag >> 1;        nt = frag & 1; }
        else if (frag < 6)  { W = msg_w2;   nt = frag - 4; }
        else if (frag < 8)  { W = gate_w;   nt = frag - 6; }
        else if (frag < 10) { W = w_dist;   nt = frag - 8; }
        else if (frag < 12) { W = coord_w1; nt = frag - 10; }
        else if (frag < 16) { W = comb_w1;  kt = (frag - 12) >> 1; nt = (frag - 12) & 1; }
        else                { W = comb_w2;  nt = frag - 16; }
        wf[t] = (unsigned short)bf16r(W[(kt * 32 + k) * 32 + nt * 16 + n16]);
    }
}

// ---------------- K3: scan level 1 ----------------
__global__ void scan1_kernel(const int* __restrict__ cnt_int, int* __restrict__ part,
                             int* __restrict__ blk) {
    __shared__ int s[SCAN_BLK];
    const int tid = threadIdx.x;
    const int i = blockIdx.x * SCAN_BLK + tid;
    const int v = (i < NNODE) ? cnt_int[i] : 0;
    s[tid] = v;
    __syncthreads();
    for (int off = 1; off < SCAN_BLK; off <<= 1) {
        int t = (tid >= off) ? s[tid - off] : 0;
        __syncthreads();
        s[tid] += t;
        __syncthreads();
    }
    part[i] = s[tid] - v;
    if (tid == SCAN_BLK - 1) blk[blockIdx.x] = s[tid];
}

// ---------------- K4: scan level 2 + emit offsets/cursor (merged scan2+scan3) ----------------
__global__ void scan23_kernel(const int* __restrict__ part, const int* __restrict__ blk,
                              int* __restrict__ offsets, int* __restrict__ cursor) {
    __shared__ int s[128];
    const int tid = threadIdx.x;
    if (tid < 128) s[tid] = (tid < NBLK1) ? blk[tid] : 0;
    __syncthreads();
    for (int off = 1; off < 128; off <<= 1) {
        int t = 0;
        if (tid < 128 && tid >= off) t = s[tid - off];
        __syncthreads();
        if (tid < 128) s[tid] += t;
        __syncthreads();
    }
    const int boff = (blockIdx.x == 0) ? 0 : s[blockIdx.x - 1];  // exclusive prefix of this block
    const int i = blockIdx.x * SCAN_BLK + tid;
    if (i < NNODE) {
        const int o = part[i] + boff;
        offsets[i] = o;
        cursor[i] = o;
    }
}

// ---------------- K5: MFMA edge kernel (R5 structure, LDS round-trips: 3 -> 2, shuffles) ----------------
__global__ __launch_bounds__(256) void edge_mfma_kernel(
    const int* __restrict__ ei, const unsigned short* __restrict__ x_bf,
    const float* __restrict__ pos,
    const float* __restrict__ rbf_means, const float* __restrict__ rbf_betas,
    const unsigned short* __restrict__ wf,
    const float* __restrict__ msg_b1, const float* __restrict__ msg_b2,
    const float* __restrict__ gate_b, const float* __restrict__ coord_b1,
    const float* __restrict__ coord_w2, const float* __restrict__ coord_b2,
    int* __restrict__ cursor, unsigned short* __restrict__ m_buf,
    float* __restrict__ pu_buf) {
    __shared__ float lmat[4][16 * 36];   // the only LDS: C->A layout bounce

    const int tid = threadIdx.x;
    const int wv = tid >> 6, lane = tid & 63;
    const int m16 = lane & 15, q = lane >> 4;
    float* Lm = lmat[wv];

    bf16x8 WF[12];
#pragma unroll
    for (int f = 0; f < 12; ++f) WF[f] = *(const bf16x8*)(wf + f * 512 + lane * 8);

    const float b1c0 = msg_b1[m16],   b1c1 = msg_b1[16 + m16];
    const float b2c0 = msg_b2[m16],   b2c1 = msg_b2[16 + m16];
    const float gbc0 = gate_b[m16],   gbc1 = gate_b[16 + m16];
    const float cb10 = coord_b1[m16], cb11 = coord_b1[16 + m16];
    const float cw20 = coord_w2[m16], cw21 = coord_w2[16 + m16];
    const float cb2  = coord_b2[0];
    const float4 rm0 = *(const float4*)(rbf_means + q * 8);
    const float4 rm1 = *(const float4*)(rbf_means + q * 8 + 4);
    const float4 rb0 = *(const float4*)(rbf_betas + q * 8);
    const float4 rb1 = *(const float4*)(rbf_betas + q * 8 + 4);

    const int wave_id = blockIdx.x * 4 + wv;
    const f32x4 z = {0.f, 0.f, 0.f, 0.f};

#pragma unroll 1
    for (int t = 0; t < TPW; ++t) {
        const int e = (wave_id * TPW + t) * 16 + m16;
        const int vi = ei[e], vj = ei[NEDGE + e];
        const bf16x8 xi = *(const bf16x8*)(x_bf + (size_t)vi * HID + q * 8);
        const bf16x8 xj = *(const bf16x8*)(x_bf + (size_t)vj * HID + q * 8);

        // geometry for edge m16 (every lane has it)
        const float p0 = pos[vi * 3 + 0] - pos[vj * 3 + 0];
        const float p1 = pos[vi * 3 + 1] - pos[vj * 3 + 1];
        const float p2 = pos[vi * 3 + 2] - pos[vj * 3 + 2];
        const float dist = sqrtf(p0 * p0 + p1 * p1 + p2 * p2);
        const float dcl = fminf(dist, 5.0f);
        const float cutoff = 0.5f * (__cosf(dcl * 0.6283185307179586f) + 1.0f);
        const float edm = __expf(-dist);

        // one atomic per edge (q==0 lanes), broadcast via shuffle
        int my_slot = 0;
        if (q == 0) my_slot = atomicAdd(&cursor[vj], 1);
        const int slot = __shfl(my_slot, m16);

        // cutoff of edge q*4+r for the C-layout combine (shuffle, issued early)
        float cu[4];
#pragma unroll
        for (int r = 0; r < 4; ++r) cu[r] = __shfl(cutoff, q * 4 + r);

        // L1: h = silu(cat(xi,xj) @ msg_w1 + b1)
        f32x4 h0 = MFMA16(xi, WF[0], z); h0 = MFMA16(xj, WF[2], h0);
        f32x4 h1 = MFMA16(xi, WF[1], z); h1 = MFMA16(xj, WF[3], h1);
#pragma unroll
        for (int r = 0; r < 4; ++r) {
            Lm[(q * 4 + r) * 36 + m16]      = silu_f(h0[r] + b1c0);
            Lm[(q * 4 + r) * 36 + 16 + m16] = silu_f(h1[r] + b1c1);
        }
        __builtin_amdgcn_s_waitcnt(0xC07F);  // lgkmcnt(0)
        f32x4 ha0 = *(const f32x4*)(Lm + m16 * 36 + q * 8);
        f32x4 ha1 = *(const f32x4*)(Lm + m16 * 36 + q * 8 + 4);
        const bf16x8 hf = pack8(ha0, ha1);

        // L2, gate, dist_emb
        f32x4 am0 = MFMA16(hf, WF[4], z), am1 = MFMA16(hf, WF[5], z);
        f32x4 g0  = MFMA16(xj, WF[6], z), g1  = MFMA16(xj, WF[7], z);
        float rv[8];
        { float d;
          d = edm - rm0.x; rv[0] = __expf(-rb0.x * d * d);
          d = edm - rm0.y; rv[1] = __expf(-rb0.y * d * d);
          d = edm - rm0.z; rv[2] = __expf(-rb0.z * d * d);
          d = edm - rm0.w; rv[3] = __expf(-rb0.w * d * d);
          d = edm - rm1.x; rv[4] = __expf(-rb1.x * d * d);
          d = edm - rm1.y; rv[5] = __expf(-rb1.y * d * d);
          d = edm - rm1.z; rv[6] = __expf(-rb1.z * d * d);
          d = edm - rm1.w; rv[7] = __expf(-rb1.w * d * d); }
        bf16x8 rf;
        { union { unsigned int u[4]; bf16x8 v; } rr;
          rr.u[0] = pk2(rv[0], rv[1]); rr.u[1] = pk2(rv[2], rv[3]);
          rr.u[2] = pk2(rv[4], rv[5]); rr.u[3] = pk2(rv[6], rv[7]);
          rf = rr.v; }
        f32x4 d0 = MFMA16(rf, WF[8], z), d1 = MFMA16(rf, WF[9], z);

        // combine in C-layout (cutoff via cu[r], no LDS dependency)
#pragma unroll
        for (int r = 0; r < 4; ++r) {
            const float mv0 = silu_f(am0[r] + b2c0) * sigmoid_f(g0[r] + gbc0) * cu[r] * d0[r];
            const float mv1 = silu_f(am1[r] + b2c1) * sigmoid_f(g1[r] + gbc1) * cu[r] * d1[r];
            Lm[(q * 4 + r) * 36 + m16]      = mv0;
            Lm[(q * 4 + r) * 36 + 16 + m16] = mv1;
        }
        __builtin_amdgcn_s_waitcnt(0xC07F);
        f32x4 ma0 = *(const f32x4*)(Lm + m16 * 36 + q * 8);
        f32x4 ma1 = *(const f32x4*)(Lm + m16 * 36 + q * 8 + 4);
        const bf16x8 mf = pack8(ma0, ma1);

        // m_buf store straight from A-layout regs: lane (q,m16) -> slot(m16)*64B + q*16B
        *(bf16x8*)(m_buf + (size_t)slot * HID + q * 8) = mf;

        // coord layer + per-edge scalar s
        f32x4 c0 = MFMA16(mf, WF[10], z), c1 = MFMA16(mf, WF[11], z);
        float pp[4];
#pragma unroll
        for (int r = 0; r < 4; ++r)
            pp[r] = silu_f(c0[r] + cb10) * cw20 + silu_f(c1[r] + cb11) * cw21;
#pragma unroll
        for (int off = 1; off < 16; off <<= 1) {
#pragma unroll
            for (int r = 0; r < 4; ++r) pp[r] += __shfl_xor(pp[r], off);
        }

        // pu store: lane (q, m16<4) writes edge ep = q*4+m16; fetch that edge's
        // pos-diff and slot via shuffle (computed pre-branch so sources are active)
        const int ep = q * 4 + (m16 & 3);
        const float sd0 = __shfl(p0, ep);
        const float sd1 = __shfl(p1, ep);
        const float sd2 = __shfl(p2, ep);
        const int slot_e = __shfl(my_slot, ep);
        const float sv = pp[m16 & 3] + cb2;
        if (m16 < 4) {
            ((float4*)pu_buf)[slot_e] = make_float4(sd0 * sv, sd1 * sv, sd2 * sv, 0.0f);
        }
    }
}

// ---------------- K6: fused gather + node post (MFMA, wave = 16 nodes) ----------------
__global__ __launch_bounds__(256) void node_post_mfma_kernel(
    const unsigned short* __restrict__ x_bf, const unsigned short* __restrict__ m_buf,
    const float* __restrict__ pu_buf,
    const int* __restrict__ offsets, const int* __restrict__ cnt_int,
    const float* __restrict__ pos, const unsigned short* __restrict__ wf,
    const float* __restrict__ comb_b1, const float* __restrict__ comb_b2,
    float* __restrict__ out_x, float* __restrict__ out_pos) {
    __shared__ float Lh[4][16 * 36];
    __shared__ float Lx[4][16 * 36];
    const int tid = threadIdx.x;
    const int wv = tid >> 6, lane = tid & 63;
    const int m16 = lane & 15, q = lane >> 4;
    const int wave_id = blockIdx.x * 4 + wv;
    if (wave_id * 16 >= NNODE) return;
    const int n = wave_id * 16 + m16;
    float* LH = Lh[wv];
    float* LX = Lx[wv];

    bf16x8 F[6];
#pragma unroll
    for (int f = 0; f < 6; ++f) F[f] = *(const bf16x8*)(wf + (12 + f) * 512 + lane * 8);
    const float b1c0 = comb_b1[m16], b1c1 = comb_b1[16 + m16];
    const float b2c0 = comb_b2[m16], b2c1 = comb_b2[16 + m16];

    const bf16x8 xa = *(const bf16x8*)(x_bf + (size_t)n * HID + q * 8);
    {
        f32x4 xd0, xd1;
#pragma unroll
        for (int jj = 0; jj < 4; ++jj) {
            xd0[jj] = bf16tof((unsigned short)xa[jj]);
            xd1[jj] = bf16tof((unsigned short)xa[4 + jj]);
        }
        *(f32x4*)(LX + m16 * 36 + q * 8) = xd0;
        *(f32x4*)(LX + m16 * 36 + q * 8 + 4) = xd1;
    }

    // gather m_i: 2-way unrolled (two loads in flight)
    const int off = offsets[n];
    const int deg = cnt_int[n];
    float acc0[8] = {0.f, 0.f, 0.f, 0.f, 0.f, 0.f, 0.f, 0.f};
    float acc1[8] = {0.f, 0.f, 0.f, 0.f, 0.f, 0.f, 0.f, 0.f};
    int d = 0;
    for (; d + 2 <= deg; d += 2) {
        const bf16x8 m0 = *(const bf16x8*)(m_buf + (size_t)(off + d) * HID + q * 8);
        const bf16x8 m1 = *(const bf16x8*)(m_buf + (size_t)(off + d + 1) * HID + q * 8);
#pragma unroll
        for (int jj = 0; jj < 8; ++jj) {
            acc0[jj] += bf16tof((unsigned short)m0[jj]);
            acc1[jj] += bf16tof((unsigned short)m1[jj]);
        }
    }
    if (d < deg) {
        const bf16x8 m0 = *(const bf16x8*)(m_buf + (size_t)(off + d) * HID + q * 8);
#pragma unroll
        for (int jj = 0; jj < 8; ++jj) acc0[jj] += bf16tof((unsigned short)m0[jj]);
    }
    bf16x8 mi;
    { union { unsigned int u[4]; bf16x8 v; } rr;
      rr.u[0] = pk2(acc0[0] + acc1[0], acc0[1] + acc1[1]);
      rr.u[1] = pk2(acc0[2] + acc1[2], acc0[3] + acc1[3]);
      rr.u[2] = pk2(acc0[4] + acc1[4], acc0[5] + acc1[5]);
      rr.u[3] = pk2(acc0[6] + acc1[6], acc0[7] + acc1[7]);
      mi = rr.v; }

    float a0 = 0.f, a1 = 0.f, a2 = 0.f;
    for (int dd = q; dd < deg; dd += 4) {
        const float4 p = ((const float4*)pu_buf)[off + dd];
        a0 += p.x; a1 += p.y; a2 += p.z;
    }
    a0 += __shfl_xor(a0, 16); a0 += __shfl_xor(a0, 32);
    a1 += __shfl_xor(a1, 16); a1 += __shfl_xor(a1, 32);
    a2 += __shfl_xor(a2, 16); a2 += __shfl_xor(a2, 32);

    const f32x4 z = {0.f, 0.f, 0.f, 0.f};
    f32x4 h0 = MFMA16(xa, F[0], z); h0 = MFMA16(mi, F[2], h0);
    f32x4 h1 = MFMA16(xa, F[1], z); h1 = MFMA16(mi, F[3], h1);
#pragma unroll
    for (int r = 0; r < 4; ++r) {
        LH[(q * 4 + r) * 36 + m16]      = silu_f(h0[r] + b1c0);
        LH[(q * 4 + r) * 36 + 16 + m16] = silu_f(h1[r] + b1c1);
    }
    __builtin_amdgcn_s_waitcnt(0xC07F);
    f32x4 ha0 = *(const f32x4*)(LH + m16 * 36 + q * 8);
    f32x4 ha1 = *(const f32x4*)(LH + m16 * 36 + q * 8 + 4);
    const bf16x8 hf = pack8(ha0, ha1);

    f32x4 c0 = MFMA16(hf, F[4], z), c1 = MFMA16(hf, F[5], z);
#pragma unroll
    for (int r = 0; r < 4; ++r) {
        const float xv0 = LX[(q * 4 + r) * 36 + m16];
        const float xv1 = LX[(q * 4 + r) * 36 + 16 + m16];
        LH[(q * 4 + r) * 36 + m16]      = silu_f(xv0 + c0[r] + b2c0);
        LH[(q * 4 + r) * 36 + 16 + m16] = silu_f(xv1 + c1[r] + b2c1);
    }
    __builtin_amdgcn_s_waitcnt(0xC07F);
    {
        const int row = lane >> 2, col = (lane & 3) * 8;
        f32x4 o0 = *(const f32x4*)(LH + row * 36 + col);
        f32x4 o1 = *(const f32x4*)(LH + row * 36 + col + 4);
        float* dst = out_x + (size_t)(wave_id * 16 + row) * HID + col;
        *(f32x4*)dst = o0;
        *(f32x4*)(dst + 4) = o1;
    }
    if (q == 0) {
        const float inv = __builtin_amdgcn_rcpf(fmaxf((float)deg, 1.0f));
        out_pos[n * 3 + 0] = fmaf(a0, inv, pos[n * 3 + 0]);
        out_pos[n * 3 + 1] = fmaf(a1, inv, pos[n * 3 + 1]);
        out_pos[n * 3 + 2] = fmaf(a2, inv, pos[n * 3 + 2]);
    }
}

// ---------------- launch ----------------
extern "C" void kernel_launch(void* const* d_in, const int* in_sizes, int n_in,
                              void* d_out, int out_size, void* d_ws, size_t ws_size,
                              hipStream_t stream) {
    const float* x        = (const float*)d_in[0];
    const int*   ei       = (const int*)d_in[1];
    const float* pos      = (const float*)d_in[2];
    const float* timein   = (const float*)d_in[3];
    const int*   batch    = (const int*)d_in[4];
    const float* rbfm     = (const float*)d_in[5];
    const float* rbfb     = (const float*)d_in[6];
    const float* w_dist   = (const float*)d_in[7];
    const float* msg_w1   = (const float*)d_in[8];
    const float* msg_b1   = (const float*)d_in[9];
    const float* msg_w2   = (const float*)d_in[10];
    const float* msg_b2   = (const float*)d_in[11];
    const float* gate_w   = (const float*)d_in[12];
    const float* gate_b   = (const float*)d_in[13];
    const float* time_w1  = (const float*)d_in[14];
    const float* time_b1  = (const float*)d_in[15];
    const float* time_w2  = (const float*)d_in[16];
    const float* time_b2  = (const float*)d_in[17];
    const float* comb_w1  = (const float*)d_in[18];
    const float* comb_b1  = (const float*)d_in[19];
    const float* comb_w2  = (const float*)d_in[20];
    const float* comb_b2  = (const float*)d_in[21];
    const float* coord_w1 = (const float*)d_in[22];
    const float* coord_b1 = (const float*)d_in[23];
    const float* coord_w2 = (const float*)d_in[24];
    const float* coord_b2 = (const float*)d_in[25];

    char* w = (char*)d_ws;
    float* ss      = (float*)w;  w += (size_t)NGRAPH * 64 * 4;
    int*   cnt_int = (int*)w;    w += (size_t)NNODE * 4;
    int*   offsets = (int*)w;    w += (size_t)NNODE * 4;
    int*   cursor  = (int*)w;    w += (size_t)NNODE * 4;
    int*   part    = (int*)w;    w += (size_t)NBLK1 * SCAN_BLK * 4;
    int*   blk     = (int*)w;    w += 128 * 4;
    w = (char*)(((size_t)w + 15) & ~(size_t)15);
    unsigned short* x_bf = (unsigned short*)w;  w += (size_t)NNODE * HID * 2;
    unsigned short* wf   = (unsigned short*)w;  w += (size_t)NFRAG * 512 * 2;
    w = (char*)(((size_t)w + 15) & ~(size_t)15);
    unsigned short* m_buf = (unsigned short*)w; w += (size_t)NEDGE * HID * 2;
    float* pu_buf  = (float*)w;

    float* out_x   = (float*)d_out;
    float* out_pos = out_x + NNODE * HID;

    time_mlp_kernel<<<NGRAPH, 64, 0, stream>>>(timein, time_w1, time_b1, time_w2, time_b2,
                                               ss, cnt_int);
    fused_pre_kernel<<<(NNODE * HID) / 256, 256, 0, stream>>>(x, batch, ss, ei, x_bf, cnt_int,
                                                              msg_w1, msg_w2, gate_w, w_dist,
                                                              coord_w1, comb_w1, comb_w2, wf);
    scan1_kernel<<<NBLK1, SCAN_BLK, 0, stream>>>(cnt_int, part, blk);
    scan23_kernel<<<NBLK1, SCAN_BLK, 0, stream>>>(part, blk, offsets, cursor);
    edge_mfma_kernel<<<NEDGE / 256, 256, 0, stream>>>(ei, x_bf, pos, rbfm, rbfb, wf,
                                                      msg_b1, msg_b2, gate_b, coord_b1,
                                                      coord_w2, coord_b2,
                                                      cursor, m_buf, pu_buf);
    node_post_mfma_kernel<<<(NNODE / 16 + 3) / 4, 256, 0, stream>>>(x_bf, m_buf, pu_buf,
                                                                    offsets, cnt_int, pos, wf,
                                                                    comb_b1, comb_b2,
                                                                    out_x, out_pos);
}